// Round 5
// baseline (325.604 us; speedup 1.0000x reference)
//
#include <hip/hip_runtime.h>
#include <hip/hip_bf16.h>
#include <math.h>

// Problem constants
#define LSEQ   4096
#define DIM    768
#define DINNER 1536
#define DSTATE 16
#define NCOLS  4640          // 3*DINNER + 2*DSTATE
#define NCH    128           // scan chunks
#define CLEN   32            // steps per chunk
#define NPAD   4736          // W_in rows padded to 37*128
#define DXW    1568          // compact f32 width: B(16) C(16) delta(1536)

typedef _Float16 f16;
typedef __attribute__((ext_vector_type(8))) _Float16 f16x8;
typedef __attribute__((ext_vector_type(4))) float f32x4;

// async global(16B/lane) -> LDS staging
__device__ __forceinline__ void gld_lds16(void* lds_dst, const void* gsrc) {
    __builtin_amdgcn_global_load_lds(
        (__attribute__((address_space(1))) void*)(gsrc),
        (__attribute__((address_space(3))) void*)(lds_dst), 16, 0, 0);
}

// ---------------------------------------------------------------------------
// GEMM1 (r2 winner, 47.2us): C = A[4096,768](f16) * B[4736,768]^T(f16).
//   BM=256 x BN=128, BK=64, 8 waves (512 thr), per-wave 64x64 (waves 4M x 2N).
//   3-deep cyclic LDS ring (144KB), prefetch distance 2, counted vmcnt(6),
//   4-phase quadrant schedule per K-tile (P00/P01/P10 with ds_read+stage,
//   P11 register-only), sched_barrier(0) after inline lgkmcnt(0) (rule #18).
//   LDS swizzle (verified conflict-free): global 16B block b of row r ->
//   LDS block b^(r&7); frag read fo=((q+4kk)^(m&7))<<3.
//   Epilogue: n0<1536 -> f16 Xb, <3072 -> f16 Zb, else f32 C (ldc=DXW).
//   NOTE (r1-r3): 2-slot dbuf @128^2 (2 blk/CU) and vmcnt(0) variants all
//   land 47-50us; MfmaUtil ~23% is this geometry's plateau at K=768.
// ---------------------------------------------------------------------------
#define G1K    768
#define G1_NT  12            // K-tiles of 64
#define G1_BM  256
#define G1_BN  128
#define G1_RT  384           // rows per K-tile (BM+BN)
#define G1_LDSE (G1_RT * 64) // f16 elems per ring slot (48KB)

__global__ __launch_bounds__(512) void gemm1_pipe(const f16* __restrict__ A,
                                                  const f16* __restrict__ B,
                                                  float* __restrict__ C,
                                                  f16* __restrict__ Xb,
                                                  f16* __restrict__ Zb) {
    __shared__ __align__(16) f16 S[3 * G1_LDSE];   // 144 KB ring

    const int P   = gridDim.x >> 3;                // XCD swizzle: 592 = 8*74
    const int idx = (blockIdx.x & 7) * P + (blockIdx.x >> 3);
    const int m0  = (idx & 15) * G1_BM;            // 16 M-tiles: B-locality slab
    const int n0  = (idx >> 4) * G1_BN;            // 37 N-tiles

    const int tid  = threadIdx.x;
    const int w    = tid >> 6;                     // wave 0..7
    const int lane = tid & 63;
    const int wr   = w >> 1;                       // 0..3 (M)
    const int wc   = w & 1;                        // 0..1 (N)
    const int m    = lane & 15;                    // fragment row(A)/col(B)
    const int q    = lane >> 4;                    // quad
    const int rl8  = lane >> 3;                    // staging: row in 8-row group
    const int bsel = lane & 7;                     // staging: 16B-block index

    // staging map: 48 x 1KB instrs per K-tile; wave w takes t = w + 8*s.
    const f16* gb[6];
#pragma unroll
    for (int s = 0; s < 6; ++s) {
        const int rl  = (w + 8 * s) * 8 + rl8;
        const int blk = bsel ^ (rl & 7);
        gb[s] = (rl < G1_BM) ? A + (size_t)(m0 + rl) * G1K + blk * 8
                             : B + (size_t)(n0 + rl - G1_BM) * G1K + blk * 8;
    }

    f32x4 acc[4][4];
#pragma unroll
    for (int i = 0; i < 4; i++)
#pragma unroll
        for (int j = 0; j < 4; j++) acc[i][j] = (f32x4){0.f, 0.f, 0.f, 0.f};

    auto stg2 = [&](int kt, int s0) {  // issue 2 of K-tile kt's 6 staging instrs
        f16* dst = S + (kt % 3) * G1_LDSE;
#pragma unroll
        for (int s = s0; s < s0 + 2; ++s)
            gld_lds16(dst + (w + 8 * s) * 512, gb[s] + kt * 64);
    };
    auto stg6 = [&](int kt) {
        f16* dst = S + (kt % 3) * G1_LDSE;
#pragma unroll
        for (int s = 0; s < 6; ++s)
            gld_lds16(dst + (w + 8 * s) * 512, gb[s] + kt * 64);
    };

    // prologue: tiles 0 and 1 in flight (12 outstanding/wave)
    stg6(0);
    stg6(1);

#pragma unroll
    for (int kt = 0; kt < G1_NT; ++kt) {
        // drain tile kt's 6 loads (oldest); tile kt+1's 6 stay in flight.
        if (kt < G1_NT - 1) asm volatile("s_waitcnt vmcnt(6)" ::: "memory");
        else                asm volatile("s_waitcnt vmcnt(0)" ::: "memory");
        __builtin_amdgcn_s_barrier();   // all waves' stg(kt) landed; slot
                                        // (kt-1)%3's readers are all past.
        const f16* As = S + (kt % 3) * G1_LDSE;
        const f16* Bs = As + G1_BM * 64;
        const bool pf = (kt + 2 < G1_NT);

        f16x8 af0[2][2], af2[2][2], bh0[2][2], bh2[2][2]; // [kk][half-idx]

        // ---- P00: read af01 + bh01 (8), stage 2, MFMA quadrant (i01 x j01)
#pragma unroll
        for (int kk = 0; kk < 2; ++kk) {
            const int fo = (((q + 4 * kk) ^ (m & 7)) << 3);
#pragma unroll
            for (int i = 0; i < 2; ++i) {
                af0[kk][i] = *(const f16x8*)&As[(wr * 64 + i * 16 + m) * 64 + fo];
                bh0[kk][i] = *(const f16x8*)&Bs[(wc * 64 + i * 16 + m) * 64 + fo];
            }
        }
        if (pf) stg2(kt + 2, 0);
        __builtin_amdgcn_s_barrier();
        asm volatile("s_waitcnt lgkmcnt(0)" ::: "memory");
        __builtin_amdgcn_sched_barrier(0);
        __builtin_amdgcn_s_setprio(1);
#pragma unroll
        for (int kk = 0; kk < 2; ++kk)
#pragma unroll
            for (int i = 0; i < 2; ++i)
#pragma unroll
                for (int j = 0; j < 2; ++j)
                    acc[i][j] = __builtin_amdgcn_mfma_f32_16x16x32_f16(
                        af0[kk][i], bh0[kk][j], acc[i][j], 0, 0, 0);
        __builtin_amdgcn_s_setprio(0);

        // ---- P01: read bh23 (4), stage 2, MFMA quadrant (i01 x j23)
#pragma unroll
        for (int kk = 0; kk < 2; ++kk) {
            const int fo = (((q + 4 * kk) ^ (m & 7)) << 3);
#pragma unroll
            for (int j = 0; j < 2; ++j)
                bh2[kk][j] = *(const f16x8*)&Bs[(wc * 64 + (j + 2) * 16 + m) * 64 + fo];
        }
        if (pf) stg2(kt + 2, 2);
        __builtin_amdgcn_s_barrier();
        asm volatile("s_waitcnt lgkmcnt(0)" ::: "memory");
        __builtin_amdgcn_sched_barrier(0);
        __builtin_amdgcn_s_setprio(1);
#pragma unroll
        for (int kk = 0; kk < 2; ++kk)
#pragma unroll
            for (int i = 0; i < 2; ++i)
#pragma unroll
                for (int j = 0; j < 2; ++j)
                    acc[i][j + 2] = __builtin_amdgcn_mfma_f32_16x16x32_f16(
                        af0[kk][i], bh2[kk][j], acc[i][j + 2], 0, 0, 0);
        __builtin_amdgcn_s_setprio(0);

        // ---- P10: read af23 (4), stage 2, MFMA quadrant (i23 x j01)
#pragma unroll
        for (int kk = 0; kk < 2; ++kk) {
            const int fo = (((q + 4 * kk) ^ (m & 7)) << 3);
#pragma unroll
            for (int i = 0; i < 2; ++i)
                af2[kk][i] = *(const f16x8*)&As[(wr * 64 + (i + 2) * 16 + m) * 64 + fo];
        }
        if (pf) stg2(kt + 2, 4);
        __builtin_amdgcn_s_barrier();
        asm volatile("s_waitcnt lgkmcnt(0)" ::: "memory");
        __builtin_amdgcn_sched_barrier(0);
        __builtin_amdgcn_s_setprio(1);
#pragma unroll
        for (int kk = 0; kk < 2; ++kk)
#pragma unroll
            for (int i = 0; i < 2; ++i)
#pragma unroll
                for (int j = 0; j < 2; ++j)
                    acc[i + 2][j] = __builtin_amdgcn_mfma_f32_16x16x32_f16(
                        af2[kk][i], bh0[kk][j], acc[i + 2][j], 0, 0, 0);
        __builtin_amdgcn_s_setprio(0);

        // ---- P11: register-only MFMA quadrant (i23 x j23), no barrier needed
        __builtin_amdgcn_s_setprio(1);
#pragma unroll
        for (int kk = 0; kk < 2; ++kk)
#pragma unroll
            for (int i = 0; i < 2; ++i)
#pragma unroll
                for (int j = 0; j < 2; ++j)
                    acc[i + 2][j + 2] = __builtin_amdgcn_mfma_f32_16x16x32_f16(
                        af2[kk][i], bh2[kk][j], acc[i + 2][j + 2], 0, 0, 0);
        __builtin_amdgcn_s_setprio(0);
    }

    // epilogue: C/D layout col=lane&15, row=q*4+reg
    if (n0 < DINNER) {                     // x_inner cols -> f16 Xb
#pragma unroll
        for (int i = 0; i < 4; i++)
#pragma unroll
            for (int j = 0; j < 4; j++) {
                const int col  = n0 + wc * 64 + j * 16 + m;
                const int rowb = m0 + wr * 64 + i * 16 + q * 4;
#pragma unroll
                for (int r = 0; r < 4; r++)
                    Xb[(size_t)(rowb + r) * DINNER + col] = (f16)acc[i][j][r];
            }
        return;
    }
    if (n0 < 2 * DINNER) {                 // z cols -> f16 Zb
#pragma unroll
        for (int i = 0; i < 4; i++)
#pragma unroll
            for (int j = 0; j < 4; j++) {
                const int col  = n0 - DINNER + wc * 64 + j * 16 + m;
                const int rowb = m0 + wr * 64 + i * 16 + q * 4;
#pragma unroll
                for (int r = 0; r < 4; r++)
                    Zb[(size_t)(rowb + r) * DINNER + col] = (f16)acc[i][j][r];
            }
        return;
    }
#pragma unroll
    for (int i = 0; i < 4; i++)            // B|C|delta -> f32 C at ldc=DXW
#pragma unroll
        for (int j = 0; j < 4; j++) {
            const int col = n0 - 2 * DINNER + wc * 64 + j * 16 + m;
            if (col >= DXW) continue;
            const int rowb = m0 + wr * 64 + i * 16 + q * 4;
#pragma unroll
            for (int r = 0; r < 4; r++)
                C[(size_t)(rowb + r) * DXW + col] = acc[i][j][r];
        }
}

// ---------------------------------------------------------------------------
// fp16 MFMA GEMM, BK=64 (2-barrier structure) — retained for GEMM2.
// ---------------------------------------------------------------------------
template<int BM, int BN, int WM, int WN, int NTB, bool COLM, bool ZMODE>
__global__ __launch_bounds__(256) void gemm_f16(const f16* __restrict__ A,
                                                const f16* __restrict__ B,
                                                float* __restrict__ C,
                                                f16* __restrict__ Xb,
                                                f16* __restrict__ Zb,
                                                int M, int N, int K, int ldc) {
    constexpr int MI  = WM / 16;
    constexpr int NI  = WN / 16;
    constexpr int NWN = BN / WN;
    constexpr int RT  = BM + BN;          // rows per k-tile
    constexpr int NS  = RT / 8;           // 1KB staging instructions per k-step

    __shared__ __align__(16) f16 S[RT * 64];
    f16* As = S;
    f16* Bs = S + BM * 64;

    const int P   = gridDim.x >> 3;
    const int idx = (blockIdx.x & 7) * P + (blockIdx.x >> 3);
    const int m0  = (COLM ? (idx % NTB) : (idx / NTB)) * BM;
    const int n0  = (COLM ? (idx / NTB) : (idx % NTB)) * BN;

    const int tid  = threadIdx.x;
    const int w    = tid >> 6;
    const int lane = tid & 63;
    const int wr   = w / NWN;
    const int wc   = w % NWN;
    const int m    = lane & 15;           // fragment row(A)/col(B)
    const int q    = lane >> 4;           // quad
    const int rl8  = lane >> 3;           // staging: row within 8-row group
    const int bsel = lane & 7;            // staging: 16B-block index

    f32x4 acc[MI][NI];
#pragma unroll
    for (int i = 0; i < MI; i++)
#pragma unroll
        for (int j = 0; j < NI; j++) acc[i][j] = (f32x4){0.f, 0.f, 0.f, 0.f};

    for (int k0 = 0; k0 < K; k0 += 64) {
#pragma unroll
        for (int t = w; t < NS; t += 4) {
            const int rl  = t * 8 + rl8;
            const int blk = bsel ^ (rl & 7);
            const f16* g = (rl < BM)
                ? A + (size_t)(m0 + rl) * K + k0 + blk * 8
                : B + (size_t)(n0 + rl - BM) * K + k0 + blk * 8;
            gld_lds16(S + t * 8 * 64, g);
        }
        __syncthreads();   // drains vmcnt(0): staging complete

#pragma unroll
        for (int kk = 0; kk < 2; kk++) {
            const int fo = (((q + 4 * kk) ^ (m & 7)) << 3);
            f16x8 af[MI], bh[NI];
#pragma unroll
            for (int i = 0; i < MI; i++)
                af[i] = *(const f16x8*)&As[(wr * WM + i * 16 + m) * 64 + fo];
#pragma unroll
            for (int j = 0; j < NI; j++)
                bh[j] = *(const f16x8*)&Bs[(wc * WN + j * 16 + m) * 64 + fo];
#pragma unroll
            for (int i = 0; i < MI; i++)
#pragma unroll
                for (int j = 0; j < NI; j++)
                    acc[i][j] = __builtin_amdgcn_mfma_f32_16x16x32_f16(
                        af[i], bh[j], acc[i][j], 0, 0, 0);
        }
        __syncthreads();
    }

    // epilogue: C/D layout col=lane&15, row=q*4+reg
    if (ZMODE && n0 < DINNER) {            // x_inner cols -> f16 Xb
#pragma unroll
        for (int i = 0; i < MI; i++)
#pragma unroll
            for (int j = 0; j < NI; j++) {
                const int col  = n0 + wc * WN + j * 16 + m;
                const int rowb = m0 + wr * WM + i * 16 + q * 4;
#pragma unroll
                for (int r = 0; r < 4; r++)
                    Xb[(size_t)(rowb + r) * DINNER + col] = (f16)acc[i][j][r];
            }
        return;
    }
    if (ZMODE && n0 < 2 * DINNER) {        // z cols -> f16 Zb
#pragma unroll
        for (int i = 0; i < MI; i++)
#pragma unroll
            for (int j = 0; j < NI; j++) {
                const int col  = n0 - DINNER + wc * WN + j * 16 + m;
                const int rowb = m0 + wr * WM + i * 16 + q * 4;
#pragma unroll
                for (int r = 0; r < 4; r++)
                    Zb[(size_t)(rowb + r) * DINNER + col] = (f16)acc[i][j][r];
            }
        return;
    }
#pragma unroll
    for (int i = 0; i < MI; i++)
#pragma unroll
        for (int j = 0; j < NI; j++) {
            const int col  = (ZMODE ? n0 - 2 * DINNER : n0) + wc * WN + j * 16 + m;
            const int lim  = ZMODE ? DXW : N;
            if (col >= lim) continue;
            const int rowb = m0 + wr * WM + i * 16 + q * 4;
#pragma unroll
            for (int r = 0; r < 4; r++)
                C[(size_t)(rowb + r) * ldc + col] = acc[i][j][r];
        }
}

// ---------------------------------------------------------------------------
// merged conversions: Ax (f16 x), Bw (f16 W_in, zero-padded), Bo (f16 W_out)
// ---------------------------------------------------------------------------
#define E0 (LSEQ * DIM)            // 3,145,728
#define E1 (E0 + NPAD * DIM)       // + 3,637,248
#define E2 (E1 + DIM * DINNER)     // + 1,179,648

__global__ __launch_bounds__(256) void cvt_all(const float* __restrict__ x,
                                               const float* __restrict__ Wi,
                                               const float* __restrict__ Wo,
                                               f16* __restrict__ Ax,
                                               f16* __restrict__ Bw,
                                               f16* __restrict__ Bo) {
    int i = (blockIdx.x * 256 + threadIdx.x) * 4;
    if (i < E0) {
        float4 v = *(const float4*)(x + i);
        Ax[i] = (f16)v.x; Ax[i+1] = (f16)v.y; Ax[i+2] = (f16)v.z; Ax[i+3] = (f16)v.w;
    } else if (i < E1) {
        int e = i - E0;
        int n = e / DIM;
        if (n < NCOLS) {
            float4 v = *(const float4*)(Wi + e);
            Bw[e] = (f16)v.x; Bw[e+1] = (f16)v.y; Bw[e+2] = (f16)v.z; Bw[e+3] = (f16)v.w;
        } else {
            Bw[e] = (f16)0.f; Bw[e+1] = (f16)0.f; Bw[e+2] = (f16)0.f; Bw[e+3] = (f16)0.f;
        }
    } else if (i < E2) {
        int e = i - E1;
        float4 v = *(const float4*)(Wo + e);
        Bo[e] = (f16)v.x; Bo[e+1] = (f16)v.y; Bo[e+2] = (f16)v.z; Bo[e+3] = (f16)v.w;
    }
}

// ---------------------------------------------------------------------------
// scan phase 1: conv+silu+softplus fused; local scan h=0 -> h_end; aprod.
// x from f16 Xb; delta/B from f32 Dxz (width DXW: B(16) C(16) delta(1536)).
// Group-pipelined t-loop: 4 groups of 8 steps; two register buffer sets
// (A/B) alternate roles by group parity. All indices unroll-time constants
// (rule #20) but live state is only 10(x)+8(d) per set -> no spill (the r4
// full-CLEN arrays hit VGPR=256 + ~50MB scratch traffic). Prefetch distance
// = 8 steps (~900cyc of compute) covers L2/L3 latency.
// ---------------------------------------------------------------------------
__global__ __launch_bounds__(256) void scan1_kernel(const float* __restrict__ Dxz,
                                                    const f16* __restrict__ Xb,
                                                    const float* __restrict__ Wc,
                                                    const float* __restrict__ A_log,
                                                    float* __restrict__ aprod,
                                                    float* __restrict__ hend) {
    __shared__ float Bs[CLEN * DSTATE];
    const int d  = blockIdx.x * 256 + threadIdx.x;
    const int c  = blockIdx.y;
    const int l0 = c * CLEN;
    for (int i = threadIdx.x; i < CLEN * DSTATE; i += 256)
        Bs[i] = Dxz[(size_t)(l0 + (i >> 4)) * DXW + (i & 15)];
    float Areg[DSTATE];
#pragma unroll
    for (int n = 0; n < DSTATE; n++) Areg[n] = -__expf(A_log[d * DSTATE + n]);
    const float w0 = Wc[d * 3 + 0], w1 = Wc[d * 3 + 1], w2 = Wc[d * 3 + 2];

    // group-0 window: xw[k] = x[l0-1+k] (k=0..9), dw[tt] = draw[l0+tt]
    float xA[10], dA_[8], xB[10], dB_[8];
    xA[0] = (l0 > 0) ? (float)Xb[(size_t)(l0 - 1) * DINNER + d] : 0.f;
#pragma unroll
    for (int k = 1; k < 10; ++k)
        xA[k] = (float)Xb[(size_t)(l0 - 1 + k) * DINNER + d];
#pragma unroll
    for (int tt = 0; tt < 8; ++tt)
        dA_[tt] = Dxz[(size_t)(l0 + tt) * DXW + 32 + d];
    __syncthreads();

    float h[DSTATE];
#pragma unroll
    for (int n = 0; n < DSTATE; n++) h[n] = 0.f;
    float S = 0.f;

#define S1_GROUP(g, xc, dc, xn, dn)                                          \
    {                                                                         \
        if (g < 3) {                                                          \
            _Pragma("unroll")                                                 \
            for (int k = 0; k < 10; ++k) {                                    \
                const int gi = l0 + 8 * ((g) + 1) - 1 + k;                    \
                xn[k] = (gi < LSEQ) ? (float)Xb[(size_t)gi * DINNER + d] : 0.f; \
            }                                                                 \
            _Pragma("unroll")                                                 \
            for (int tt = 0; tt < 8; ++tt)                                    \
                dn[tt] = Dxz[(size_t)(l0 + 8 * ((g) + 1) + tt) * DXW + 32 + d]; \
        }                                                                     \
        _Pragma("unroll")                                                     \
        for (int tt = 0; tt < 8; ++tt) {                                      \
            const int t = 8 * (g) + tt;                                       \
            float v   = xc[tt] * w0 + xc[tt + 1] * w1 + xc[tt + 2] * w2;      \
            float xcv = __fdividef(v, 1.f + __expf(-v));                      \
            float draw = dc[tt];                                              \
            float dtv = (draw > 20.f) ? draw : __logf(1.f + __expf(draw));    \
            float u = dtv * xcv;                                              \
            S += dtv;                                                         \
            _Pragma("unroll")                                                 \
            for (int n = 0; n < DSTATE; n++) {                                \
                float e = __expf(dtv * Areg[n]);                              \
                h[n] = e * h[n] + u * Bs[t * DSTATE + n];                     \
            }                                                                 \
        }                                                                     \
    }

    S1_GROUP(0, xA, dA_, xB, dB_)
    S1_GROUP(1, xB, dB_, xA, dA_)
    S1_GROUP(2, xA, dA_, xB, dB_)
    S1_GROUP(3, xB, dB_, xA, dA_)
#undef S1_GROUP

#pragma unroll
    for (int n = 0; n < DSTATE; n++) {
        size_t idx = ((size_t)c * DSTATE + n) * DINNER + d;
        aprod[idx] = __expf(S * Areg[n]);
        hend[idx]  = h[n];
    }
}

// ---------------------------------------------------------------------------
// scan phase 2: sequential over NCH chunk summaries, pipelined loads
// ---------------------------------------------------------------------------
__global__ __launch_bounds__(256) void scan2_kernel(const float* __restrict__ aprod,
                                                    const float* __restrict__ hend,
                                                    float* __restrict__ hinit) {
    const int g = blockIdx.x * 256 + threadIdx.x;
    const size_t S = (size_t)DSTATE * DINNER;
    size_t idx = g;
    float a = aprod[idx], e = hend[idx];
    float h = 0.f;
#pragma unroll 4
    for (int c = 0; c < NCH; c++) {
        float ac = a, ec = e;
        if (c + 1 < NCH) { a = aprod[idx + S]; e = hend[idx + S]; }
        hinit[idx] = h;
        h = ac * h + ec;
        idx += S;
    }
}

// ---------------------------------------------------------------------------
// scan phase 3: replay from h_init; z-gate from f16 Zb; emit f16 Ay.
// Same group-pipelined structure as scan1 (+z stream, +C/y/output).
// ---------------------------------------------------------------------------
__global__ __launch_bounds__(256) void scan3_kernel(const float* __restrict__ Dxz,
                                                    const f16* __restrict__ Xb,
                                                    const f16* __restrict__ Zb,
                                                    const float* __restrict__ Wc,
                                                    const float* __restrict__ A_log,
                                                    const float* __restrict__ hinit,
                                                    const float* __restrict__ Dp,
                                                    f16* __restrict__ Ay) {
    __shared__ float Bs[CLEN * DSTATE];
    __shared__ float Cs[CLEN * DSTATE];
    const int d  = blockIdx.x * 256 + threadIdx.x;
    const int c  = blockIdx.y;
    const int l0 = c * CLEN;
    for (int i = threadIdx.x; i < CLEN * DSTATE; i += 256) {
        size_t roff = (size_t)(l0 + (i >> 4)) * DXW;
        Bs[i] = Dxz[roff + (i & 15)];
        Cs[i] = Dxz[roff + 16 + (i & 15)];
    }
    float h[DSTATE];
#pragma unroll
    for (int n = 0; n < DSTATE; n++)
        h[n] = hinit[((size_t)c * DSTATE + n) * DINNER + d];
    float Areg[DSTATE];
#pragma unroll
    for (int n = 0; n < DSTATE; n++) Areg[n] = -__expf(A_log[d * DSTATE + n]);
    const float Dv = Dp[d];
    const float w0 = Wc[d * 3 + 0], w1 = Wc[d * 3 + 1], w2 = Wc[d * 3 + 2];

    float xA[10], dA_[8], zA[8], xB[10], dB_[8], zB[8];
    xA[0] = (l0 > 0) ? (float)Xb[(size_t)(l0 - 1) * DINNER + d] : 0.f;
#pragma unroll
    for (int k = 1; k < 10; ++k)
        xA[k] = (float)Xb[(size_t)(l0 - 1 + k) * DINNER + d];
#pragma unroll
    for (int tt = 0; tt < 8; ++tt) {
        dA_[tt] = Dxz[(size_t)(l0 + tt) * DXW + 32 + d];
        zA[tt]  = (float)Zb[(size_t)(l0 + tt) * DINNER + d];
    }
    __syncthreads();

#define S3_GROUP(g, xc, dc, zc, xn, dn, zn)                                  \
    {                                                                         \
        if (g < 3) {                                                          \
            _Pragma("unroll")                                                 \
            for (int k = 0; k < 10; ++k) {                                    \
                const int gi = l0 + 8 * ((g) + 1) - 1 + k;                    \
                xn[k] = (gi < LSEQ) ? (float)Xb[(size_t)gi * DINNER + d] : 0.f; \
            }                                                                 \
            _Pragma("unroll")                                                 \
            for (int tt = 0; tt < 8; ++tt) {                                  \
                dn[tt] = Dxz[(size_t)(l0 + 8 * ((g) + 1) + tt) * DXW + 32 + d]; \
                zn[tt] = (float)Zb[(size_t)(l0 + 8 * ((g) + 1) + tt) * DINNER + d]; \
            }                                                                 \
        }                                                                     \
        _Pragma("unroll")                                                     \
        for (int tt = 0; tt < 8; ++tt) {                                      \
            const int t = 8 * (g) + tt;                                       \
            float v   = xc[tt] * w0 + xc[tt + 1] * w1 + xc[tt + 2] * w2;      \
            float xcv = __fdividef(v, 1.f + __expf(-v));                      \
            float draw = dc[tt];                                              \
            float dtv = (draw > 20.f) ? draw : __logf(1.f + __expf(draw));    \
            float u = dtv * xcv;                                              \
            float y = 0.f;                                                    \
            _Pragma("unroll")                                                 \
            for (int n = 0; n < DSTATE; n++) {                                \
                float e = __expf(dtv * Areg[n]);                              \
                h[n] = e * h[n] + u * Bs[t * DSTATE + n];                     \
                y += h[n] * Cs[t * DSTATE + n];                               \
            }                                                                 \
            float sz = __fdividef(zc[tt], 1.f + __expf(-zc[tt]));             \
            Ay[(size_t)(l0 + t) * DINNER + d] = (f16)((y + xcv * Dv) * sz);   \
        }                                                                     \
    }

    S3_GROUP(0, xA, dA_, zA, xB, dB_, zB)
    S3_GROUP(1, xB, dB_, zB, xA, dA_, zA)
    S3_GROUP(2, xA, dA_, zA, xB, dB_, zB)
    S3_GROUP(3, xB, dB_, zB, xA, dA_, zA)
#undef S3_GROUP
}

// ---------------------------------------------------------------------------
extern "C" void kernel_launch(void* const* d_in, const int* in_sizes, int n_in,
                              void* d_out, int out_size, void* d_ws, size_t ws_size,
                              hipStream_t stream) {
    const float* x     = (const float*)d_in[0];
    const float* W_in  = (const float*)d_in[1];
    const float* W_conv= (const float*)d_in[2];
    const float* W_out = (const float*)d_in[3];
    const float* A_log = (const float*)d_in[4];
    const float* Dp    = (const float*)d_in[5];
    float* out = (float*)d_out;

    // workspace carve-up (~117 MB)
    float* ws  = (float*)d_ws;
    float* Dxz = ws;                                  // 4096*1568 f32
    float* ap  = Dxz + (size_t)LSEQ * DXW;            // 3,145,728
    float* he  = ap + (size_t)NCH * DSTATE * DINNER;  // 3,145,728
    float* hi  = he + (size_t)NCH * DSTATE * DINNER;  // 3,145,728
    f16* Ax = (f16*)(hi + (size_t)NCH * DSTATE * DINNER); // 4096*768
    f16* Ay = Ax + (size_t)LSEQ * DIM;                // 4096*1536
    f16* Bw = Ay + (size_t)LSEQ * DINNER;             // 4736*768
    f16* Bo = Bw + (size_t)NPAD * DIM;                // 768*1536
    f16* Zb = Bo + (size_t)DIM * DINNER;              // 4096*1536
    f16* Xb = Zb + (size_t)LSEQ * DINNER;             // 4096*1536

    // 0) conversions (one kernel)
    cvt_all<<<E2 / 1024, 256, 0, stream>>>(x, W_in, W_out, Ax, Bw, Bo);

    // 1) xz = x @ W_in^T : 4-phase pipelined 256x128 tiles, counted vmcnt(6).
    //    16 M-tiles x 37 N-tiles = 592 blocks (= 8*74, XCD swizzle),
    //    col-major slab (B-locality per XCD).
    gemm1_pipe<<<592, 512, 0, stream>>>(Ax, Bw, Dxz, Xb, Zb);

    // 2) chunked scan
    scan1_kernel<<<dim3(DINNER / 256, NCH), 256, 0, stream>>>(
        Dxz, Xb, W_conv, A_log, ap, he);
    scan2_kernel<<<(DINNER * DSTATE) / 256, 256, 0, stream>>>(ap, he, hi);
    scan3_kernel<<<dim3(DINNER / 256, NCH), 256, 0, stream>>>(
        Dxz, Xb, Zb, W_conv, A_log, hi, Dp, Ay);

    // 3) out = yf @ W_out^T : BK=64, single-plane f16 W_out.
    //    64 M-tiles x 12 N-tiles = 768 blocks, row-major XCD slab (A-locality)
    gemm_f16<64, 64, 32, 32, 12, false, false><<<768, 256, 0, stream>>>(
        Ay, Bo, out, nullptr, nullptr, LSEQ, DIM, DINNER, DIM);
}

// Round 6
// 247.763 us; speedup vs baseline: 1.3142x; 1.3142x over previous
//
#include <hip/hip_runtime.h>
#include <hip/hip_bf16.h>
#include <math.h>

// Problem constants
#define LSEQ   4096
#define DIM    768
#define DINNER 1536
#define DSTATE 16
#define NCOLS  4640          // 3*DINNER + 2*DSTATE
#define NCH    256           // scan chunks (r6: 128->256, halves serial chain)
#define CLEN   16            // steps per chunk (r6: 32->16)
#define NPAD   4736          // W_in rows padded to 37*128
#define DXW    1568          // compact f32 width: B(16) C(16) delta(1536)

typedef _Float16 f16;
typedef __attribute__((ext_vector_type(8))) _Float16 f16x8;
typedef __attribute__((ext_vector_type(4))) float f32x4;

// async global(16B/lane) -> LDS staging
__device__ __forceinline__ void gld_lds16(void* lds_dst, const void* gsrc) {
    __builtin_amdgcn_global_load_lds(
        (__attribute__((address_space(1))) void*)(gsrc),
        (__attribute__((address_space(3))) void*)(lds_dst), 16, 0, 0);
}

// ---------------------------------------------------------------------------
// GEMM1 (r2 winner, 47.2us): C = A[4096,768](f16) * B[4736,768]^T(f16).
//   BM=256 x BN=128, BK=64, 8 waves (512 thr), per-wave 64x64 (waves 4M x 2N).
//   3-deep cyclic LDS ring (144KB), prefetch distance 2, counted vmcnt(6),
//   4-phase quadrant schedule per K-tile (P00/P01/P10 with ds_read+stage,
//   P11 register-only), sched_barrier(0) after inline lgkmcnt(0) (rule #18).
//   LDS swizzle (verified conflict-free): global 16B block b of row r ->
//   LDS block b^(r&7); frag read fo=((q+4kk)^(m&7))<<3.
//   Epilogue: n0<1536 -> f16 Xb, <3072 -> f16 Zb, else f32 C (ldc=DXW).
//   NOTE (r1-r3): 2-slot dbuf @128^2 (2 blk/CU) and vmcnt(0) variants all
//   land 47-50us; MfmaUtil ~23% is this geometry's plateau at K=768.
// ---------------------------------------------------------------------------
#define G1K    768
#define G1_NT  12            // K-tiles of 64
#define G1_BM  256
#define G1_BN  128
#define G1_RT  384           // rows per K-tile (BM+BN)
#define G1_LDSE (G1_RT * 64) // f16 elems per ring slot (48KB)

__global__ __launch_bounds__(512) void gemm1_pipe(const f16* __restrict__ A,
                                                  const f16* __restrict__ B,
                                                  float* __restrict__ C,
                                                  f16* __restrict__ Xb,
                                                  f16* __restrict__ Zb) {
    __shared__ __align__(16) f16 S[3 * G1_LDSE];   // 144 KB ring

    const int P   = gridDim.x >> 3;                // XCD swizzle: 592 = 8*74
    const int idx = (blockIdx.x & 7) * P + (blockIdx.x >> 3);
    const int m0  = (idx & 15) * G1_BM;            // 16 M-tiles: B-locality slab
    const int n0  = (idx >> 4) * G1_BN;            // 37 N-tiles

    const int tid  = threadIdx.x;
    const int w    = tid >> 6;                     // wave 0..7
    const int lane = tid & 63;
    const int wr   = w >> 1;                       // 0..3 (M)
    const int wc   = w & 1;                        // 0..1 (N)
    const int m    = lane & 15;                    // fragment row(A)/col(B)
    const int q    = lane >> 4;                    // quad
    const int rl8  = lane >> 3;                    // staging: row in 8-row group
    const int bsel = lane & 7;                     // staging: 16B-block index

    // staging map: 48 x 1KB instrs per K-tile; wave w takes t = w + 8*s.
    const f16* gb[6];
#pragma unroll
    for (int s = 0; s < 6; ++s) {
        const int rl  = (w + 8 * s) * 8 + rl8;
        const int blk = bsel ^ (rl & 7);
        gb[s] = (rl < G1_BM) ? A + (size_t)(m0 + rl) * G1K + blk * 8
                             : B + (size_t)(n0 + rl - G1_BM) * G1K + blk * 8;
    }

    f32x4 acc[4][4];
#pragma unroll
    for (int i = 0; i < 4; i++)
#pragma unroll
        for (int j = 0; j < 4; j++) acc[i][j] = (f32x4){0.f, 0.f, 0.f, 0.f};

    auto stg2 = [&](int kt, int s0) {  // issue 2 of K-tile kt's 6 staging instrs
        f16* dst = S + (kt % 3) * G1_LDSE;
#pragma unroll
        for (int s = s0; s < s0 + 2; ++s)
            gld_lds16(dst + (w + 8 * s) * 512, gb[s] + kt * 64);
    };
    auto stg6 = [&](int kt) {
        f16* dst = S + (kt % 3) * G1_LDSE;
#pragma unroll
        for (int s = 0; s < 6; ++s)
            gld_lds16(dst + (w + 8 * s) * 512, gb[s] + kt * 64);
    };

    // prologue: tiles 0 and 1 in flight (12 outstanding/wave)
    stg6(0);
    stg6(1);

#pragma unroll
    for (int kt = 0; kt < G1_NT; ++kt) {
        // drain tile kt's 6 loads (oldest); tile kt+1's 6 stay in flight.
        if (kt < G1_NT - 1) asm volatile("s_waitcnt vmcnt(6)" ::: "memory");
        else                asm volatile("s_waitcnt vmcnt(0)" ::: "memory");
        __builtin_amdgcn_s_barrier();   // all waves' stg(kt) landed; slot
                                        // (kt-1)%3's readers are all past.
        const f16* As = S + (kt % 3) * G1_LDSE;
        const f16* Bs = As + G1_BM * 64;
        const bool pf = (kt + 2 < G1_NT);

        f16x8 af0[2][2], af2[2][2], bh0[2][2], bh2[2][2]; // [kk][half-idx]

        // ---- P00: read af01 + bh01 (8), stage 2, MFMA quadrant (i01 x j01)
#pragma unroll
        for (int kk = 0; kk < 2; ++kk) {
            const int fo = (((q + 4 * kk) ^ (m & 7)) << 3);
#pragma unroll
            for (int i = 0; i < 2; ++i) {
                af0[kk][i] = *(const f16x8*)&As[(wr * 64 + i * 16 + m) * 64 + fo];
                bh0[kk][i] = *(const f16x8*)&Bs[(wc * 64 + i * 16 + m) * 64 + fo];
            }
        }
        if (pf) stg2(kt + 2, 0);
        __builtin_amdgcn_s_barrier();
        asm volatile("s_waitcnt lgkmcnt(0)" ::: "memory");
        __builtin_amdgcn_sched_barrier(0);
        __builtin_amdgcn_s_setprio(1);
#pragma unroll
        for (int kk = 0; kk < 2; ++kk)
#pragma unroll
            for (int i = 0; i < 2; ++i)
#pragma unroll
                for (int j = 0; j < 2; ++j)
                    acc[i][j] = __builtin_amdgcn_mfma_f32_16x16x32_f16(
                        af0[kk][i], bh0[kk][j], acc[i][j], 0, 0, 0);
        __builtin_amdgcn_s_setprio(0);

        // ---- P01: read bh23 (4), stage 2, MFMA quadrant (i01 x j23)
#pragma unroll
        for (int kk = 0; kk < 2; ++kk) {
            const int fo = (((q + 4 * kk) ^ (m & 7)) << 3);
#pragma unroll
            for (int j = 0; j < 2; ++j)
                bh2[kk][j] = *(const f16x8*)&Bs[(wc * 64 + (j + 2) * 16 + m) * 64 + fo];
        }
        if (pf) stg2(kt + 2, 2);
        __builtin_amdgcn_s_barrier();
        asm volatile("s_waitcnt lgkmcnt(0)" ::: "memory");
        __builtin_amdgcn_sched_barrier(0);
        __builtin_amdgcn_s_setprio(1);
#pragma unroll
        for (int kk = 0; kk < 2; ++kk)
#pragma unroll
            for (int i = 0; i < 2; ++i)
#pragma unroll
                for (int j = 0; j < 2; ++j)
                    acc[i][j + 2] = __builtin_amdgcn_mfma_f32_16x16x32_f16(
                        af0[kk][i], bh2[kk][j], acc[i][j + 2], 0, 0, 0);
        __builtin_amdgcn_s_setprio(0);

        // ---- P10: read af23 (4), stage 2, MFMA quadrant (i23 x j01)
#pragma unroll
        for (int kk = 0; kk < 2; ++kk) {
            const int fo = (((q + 4 * kk) ^ (m & 7)) << 3);
#pragma unroll
            for (int i = 0; i < 2; ++i)
                af2[kk][i] = *(const f16x8*)&As[(wr * 64 + (i + 2) * 16 + m) * 64 + fo];
        }
        if (pf) stg2(kt + 2, 4);
        __builtin_amdgcn_s_barrier();
        asm volatile("s_waitcnt lgkmcnt(0)" ::: "memory");
        __builtin_amdgcn_sched_barrier(0);
        __builtin_amdgcn_s_setprio(1);
#pragma unroll
        for (int kk = 0; kk < 2; ++kk)
#pragma unroll
            for (int i = 0; i < 2; ++i)
#pragma unroll
                for (int j = 0; j < 2; ++j)
                    acc[i + 2][j] = __builtin_amdgcn_mfma_f32_16x16x32_f16(
                        af2[kk][i], bh0[kk][j], acc[i + 2][j], 0, 0, 0);
        __builtin_amdgcn_s_setprio(0);

        // ---- P11: register-only MFMA quadrant (i23 x j23), no barrier needed
        __builtin_amdgcn_s_setprio(1);
#pragma unroll
        for (int kk = 0; kk < 2; ++kk)
#pragma unroll
            for (int i = 0; i < 2; ++i)
#pragma unroll
                for (int j = 0; j < 2; ++j)
                    acc[i + 2][j + 2] = __builtin_amdgcn_mfma_f32_16x16x32_f16(
                        af2[kk][i], bh2[kk][j], acc[i + 2][j + 2], 0, 0, 0);
        __builtin_amdgcn_s_setprio(0);
    }

    // epilogue: C/D layout col=lane&15, row=q*4+reg
    if (n0 < DINNER) {                     // x_inner cols -> f16 Xb
#pragma unroll
        for (int i = 0; i < 4; i++)
#pragma unroll
            for (int j = 0; j < 4; j++) {
                const int col  = n0 + wc * 64 + j * 16 + m;
                const int rowb = m0 + wr * 64 + i * 16 + q * 4;
#pragma unroll
                for (int r = 0; r < 4; r++)
                    Xb[(size_t)(rowb + r) * DINNER + col] = (f16)acc[i][j][r];
            }
        return;
    }
    if (n0 < 2 * DINNER) {                 // z cols -> f16 Zb
#pragma unroll
        for (int i = 0; i < 4; i++)
#pragma unroll
            for (int j = 0; j < 4; j++) {
                const int col  = n0 - DINNER + wc * 64 + j * 16 + m;
                const int rowb = m0 + wr * 64 + i * 16 + q * 4;
#pragma unroll
                for (int r = 0; r < 4; r++)
                    Zb[(size_t)(rowb + r) * DINNER + col] = (f16)acc[i][j][r];
            }
        return;
    }
#pragma unroll
    for (int i = 0; i < 4; i++)            // B|C|delta -> f32 C at ldc=DXW
#pragma unroll
        for (int j = 0; j < 4; j++) {
            const int col = n0 - 2 * DINNER + wc * 64 + j * 16 + m;
            if (col >= DXW) continue;
            const int rowb = m0 + wr * 64 + i * 16 + q * 4;
#pragma unroll
            for (int r = 0; r < 4; r++)
                C[(size_t)(rowb + r) * DXW + col] = acc[i][j][r];
        }
}

// ---------------------------------------------------------------------------
// fp16 MFMA GEMM, BK=64 (2-barrier structure) — retained for GEMM2.
// ---------------------------------------------------------------------------
template<int BM, int BN, int WM, int WN, int NTB, bool COLM, bool ZMODE>
__global__ __launch_bounds__(256) void gemm_f16(const f16* __restrict__ A,
                                                const f16* __restrict__ B,
                                                float* __restrict__ C,
                                                f16* __restrict__ Xb,
                                                f16* __restrict__ Zb,
                                                int M, int N, int K, int ldc) {
    constexpr int MI  = WM / 16;
    constexpr int NI  = WN / 16;
    constexpr int NWN = BN / WN;
    constexpr int RT  = BM + BN;          // rows per k-tile
    constexpr int NS  = RT / 8;           // 1KB staging instructions per k-step

    __shared__ __align__(16) f16 S[RT * 64];
    f16* As = S;
    f16* Bs = S + BM * 64;

    const int P   = gridDim.x >> 3;
    const int idx = (blockIdx.x & 7) * P + (blockIdx.x >> 3);
    const int m0  = (COLM ? (idx % NTB) : (idx / NTB)) * BM;
    const int n0  = (COLM ? (idx / NTB) : (idx % NTB)) * BN;

    const int tid  = threadIdx.x;
    const int w    = tid >> 6;
    const int lane = tid & 63;
    const int wr   = w / NWN;
    const int wc   = w % NWN;
    const int m    = lane & 15;           // fragment row(A)/col(B)
    const int q    = lane >> 4;           // quad
    const int rl8  = lane >> 3;           // staging: row within 8-row group
    const int bsel = lane & 7;            // staging: 16B-block index

    f32x4 acc[MI][NI];
#pragma unroll
    for (int i = 0; i < MI; i++)
#pragma unroll
        for (int j = 0; j < NI; j++) acc[i][j] = (f32x4){0.f, 0.f, 0.f, 0.f};

    for (int k0 = 0; k0 < K; k0 += 64) {
#pragma unroll
        for (int t = w; t < NS; t += 4) {
            const int rl  = t * 8 + rl8;
            const int blk = bsel ^ (rl & 7);
            const f16* g = (rl < BM)
                ? A + (size_t)(m0 + rl) * K + k0 + blk * 8
                : B + (size_t)(n0 + rl - BM) * K + k0 + blk * 8;
            gld_lds16(S + t * 8 * 64, g);
        }
        __syncthreads();   // drains vmcnt(0): staging complete

#pragma unroll
        for (int kk = 0; kk < 2; kk++) {
            const int fo = (((q + 4 * kk) ^ (m & 7)) << 3);
            f16x8 af[MI], bh[NI];
#pragma unroll
            for (int i = 0; i < MI; i++)
                af[i] = *(const f16x8*)&As[(wr * WM + i * 16 + m) * 64 + fo];
#pragma unroll
            for (int j = 0; j < NI; j++)
                bh[j] = *(const f16x8*)&Bs[(wc * WN + j * 16 + m) * 64 + fo];
#pragma unroll
            for (int i = 0; i < MI; i++)
#pragma unroll
                for (int j = 0; j < NI; j++)
                    acc[i][j] = __builtin_amdgcn_mfma_f32_16x16x32_f16(
                        af[i], bh[j], acc[i][j], 0, 0, 0);
        }
        __syncthreads();
    }

    // epilogue: C/D layout col=lane&15, row=q*4+reg
    if (ZMODE && n0 < DINNER) {            // x_inner cols -> f16 Xb
#pragma unroll
        for (int i = 0; i < MI; i++)
#pragma unroll
            for (int j = 0; j < NI; j++) {
                const int col  = n0 + wc * WN + j * 16 + m;
                const int rowb = m0 + wr * WM + i * 16 + q * 4;
#pragma unroll
                for (int r = 0; r < 4; r++)
                    Xb[(size_t)(rowb + r) * DINNER + col] = (f16)acc[i][j][r];
            }
        return;
    }
    if (ZMODE && n0 < 2 * DINNER) {        // z cols -> f16 Zb
#pragma unroll
        for (int i = 0; i < MI; i++)
#pragma unroll
            for (int j = 0; j < NI; j++) {
                const int col  = n0 - DINNER + wc * WN + j * 16 + m;
                const int rowb = m0 + wr * WM + i * 16 + q * 4;
#pragma unroll
                for (int r = 0; r < 4; r++)
                    Zb[(size_t)(rowb + r) * DINNER + col] = (f16)acc[i][j][r];
            }
        return;
    }
#pragma unroll
    for (int i = 0; i < MI; i++)
#pragma unroll
        for (int j = 0; j < NI; j++) {
            const int col  = (ZMODE ? n0 - 2 * DINNER : n0) + wc * WN + j * 16 + m;
            const int lim  = ZMODE ? DXW : N;
            if (col >= lim) continue;
            const int rowb = m0 + wr * WM + i * 16 + q * 4;
#pragma unroll
            for (int r = 0; r < 4; r++)
                C[(size_t)(rowb + r) * ldc + col] = acc[i][j][r];
        }
}

// ---------------------------------------------------------------------------
// merged conversions: Ax (f16 x), Bw (f16 W_in, zero-padded), Bo (f16 W_out)
// ---------------------------------------------------------------------------
#define E0 (LSEQ * DIM)            // 3,145,728
#define E1 (E0 + NPAD * DIM)       // + 3,637,248
#define E2 (E1 + DIM * DINNER)     // + 1,179,648

__global__ __launch_bounds__(256) void cvt_all(const float* __restrict__ x,
                                               const float* __restrict__ Wi,
                                               const float* __restrict__ Wo,
                                               f16* __restrict__ Ax,
                                               f16* __restrict__ Bw,
                                               f16* __restrict__ Bo) {
    int i = (blockIdx.x * 256 + threadIdx.x) * 4;
    if (i < E0) {
        float4 v = *(const float4*)(x + i);
        Ax[i] = (f16)v.x; Ax[i+1] = (f16)v.y; Ax[i+2] = (f16)v.z; Ax[i+3] = (f16)v.w;
    } else if (i < E1) {
        int e = i - E0;
        int n = e / DIM;
        if (n < NCOLS) {
            float4 v = *(const float4*)(Wi + e);
            Bw[e] = (f16)v.x; Bw[e+1] = (f16)v.y; Bw[e+2] = (f16)v.z; Bw[e+3] = (f16)v.w;
        } else {
            Bw[e] = (f16)0.f; Bw[e+1] = (f16)0.f; Bw[e+2] = (f16)0.f; Bw[e+3] = (f16)0.f;
        }
    } else if (i < E2) {
        int e = i - E1;
        float4 v = *(const float4*)(Wo + e);
        Bo[e] = (f16)v.x; Bo[e+1] = (f16)v.y; Bo[e+2] = (f16)v.z; Bo[e+3] = (f16)v.w;
    }
}

// ---------------------------------------------------------------------------
// scan phase 1 (r0 rolling form, CLEN=16): conv+silu+softplus fused; local
// scan h=0 -> h_end; aprod. Rolling scalar prefetch distance 1 (known-good;
// r4 full-CLEN arrays spilled, r5 group-pipeline was latency-worse). The
// occupancy lever is NCH=256: grid 6x256=1536 blocks -> 6 blocks/CU ->
// ~24 waves/CU (2x r0-r5) and half the serial chain per wave.
// ---------------------------------------------------------------------------
__global__ __launch_bounds__(256) void scan1_kernel(const float* __restrict__ Dxz,
                                                    const f16* __restrict__ Xb,
                                                    const float* __restrict__ Wc,
                                                    const float* __restrict__ A_log,
                                                    float* __restrict__ aprod,
                                                    float* __restrict__ hend) {
    __shared__ float Bs[CLEN * DSTATE];
    const int d  = blockIdx.x * 256 + threadIdx.x;
    const int c  = blockIdx.y;
    const int l0 = c * CLEN;
    for (int i = threadIdx.x; i < CLEN * DSTATE; i += 256)
        Bs[i] = Dxz[(size_t)(l0 + (i >> 4)) * DXW + (i & 15)];
    float Areg[DSTATE];
#pragma unroll
    for (int n = 0; n < DSTATE; n++) Areg[n] = -__expf(A_log[d * DSTATE + n]);
    const float w0 = Wc[d * 3 + 0], w1 = Wc[d * 3 + 1], w2 = Wc[d * 3 + 2];
    float xm = (l0 > 0) ? (float)Xb[(size_t)(l0 - 1) * DINNER + d] : 0.f;
    float x0 = (float)Xb[(size_t)l0 * DINNER + d];
    float ld_xp   = (float)Xb[(size_t)(l0 + 1) * DINNER + d];
    float ld_draw = Dxz[(size_t)l0 * DXW + 32 + d];
    __syncthreads();

    float h[DSTATE];
#pragma unroll
    for (int n = 0; n < DSTATE; n++) h[n] = 0.f;
    float S = 0.f;

    for (int t = 0; t < CLEN; t++) {
        const int l = l0 + t;
        float xp = ld_xp, draw = ld_draw;
        if (t + 1 < CLEN) {
            ld_xp   = (l + 2 < LSEQ) ? (float)Xb[(size_t)(l + 2) * DINNER + d] : 0.f;
            ld_draw = Dxz[(size_t)(l + 1) * DXW + 32 + d];
        }
        float v  = xm * w0 + x0 * w1 + xp * w2;
        float xcv = __fdividef(v, 1.f + __expf(-v));
        float dtv = (draw > 20.f) ? draw : __logf(1.f + __expf(draw));
        float u = dtv * xcv;
        S += dtv;
#pragma unroll
        for (int n = 0; n < DSTATE; n++) {
            float e = __expf(dtv * Areg[n]);
            h[n] = e * h[n] + u * Bs[t * DSTATE + n];
        }
        xm = x0; x0 = xp;
    }
#pragma unroll
    for (int n = 0; n < DSTATE; n++) {
        size_t idx = ((size_t)c * DSTATE + n) * DINNER + d;
        aprod[idx] = __expf(S * Areg[n]);
        hend[idx]  = h[n];
    }
}

// ---------------------------------------------------------------------------
// scan phase 2: sequential over NCH chunk summaries. 4-deep batched prefetch
// (two named 4-buffers, static indices — rule #20). Writes hinit IN-PLACE
// into the aprod buffer: each thread owns its (n,d) column, and aphi[c] is
// read 4-8 chunks before the hinit store to the same address -> race-free,
// saves a 25MB workspace buffer at NCH=256.
// ---------------------------------------------------------------------------
__global__ __launch_bounds__(256) void scan2_kernel(float* __restrict__ aphi,
                                                    const float* __restrict__ hend) {
    const int g = blockIdx.x * 256 + threadIdx.x;
    const size_t S = (size_t)DSTATE * DINNER;
    float aA[4], eA[4], aB[4], eB[4];
#pragma unroll
    for (int k = 0; k < 4; ++k) {
        aA[k] = aphi[g + (size_t)k * S];
        eA[k] = hend[g + (size_t)k * S];
    }
    float h = 0.f;
    for (int c = 0; c < NCH; c += 8) {
#pragma unroll
        for (int k = 0; k < 4; ++k) {      // prefetch B: chunks c+4..c+7
            aB[k] = aphi[g + (size_t)(c + 4 + k) * S];
            eB[k] = hend[g + (size_t)(c + 4 + k) * S];
        }
#pragma unroll
        for (int k = 0; k < 4; ++k) {      // process A: chunks c..c+3
            aphi[g + (size_t)(c + k) * S] = h;     // hinit (in-place)
            h = aA[k] * h + eA[k];
        }
        if (c + 8 < NCH) {
#pragma unroll
            for (int k = 0; k < 4; ++k) {  // prefetch A: chunks c+8..c+11
                aA[k] = aphi[g + (size_t)(c + 8 + k) * S];
                eA[k] = hend[g + (size_t)(c + 8 + k) * S];
            }
        }
#pragma unroll
        for (int k = 0; k < 4; ++k) {      // process B: chunks c+4..c+7
            aphi[g + (size_t)(c + 4 + k) * S] = h; // hinit (in-place)
            h = aB[k] * h + eB[k];
        }
    }
}

// ---------------------------------------------------------------------------
// scan phase 3 (r0 rolling form, CLEN=16): replay from h_init (aliased into
// the aprod buffer); z-gate from f16 Zb; emit f16 Ay.
// ---------------------------------------------------------------------------
__global__ __launch_bounds__(256) void scan3_kernel(const float* __restrict__ Dxz,
                                                    const f16* __restrict__ Xb,
                                                    const f16* __restrict__ Zb,
                                                    const float* __restrict__ Wc,
                                                    const float* __restrict__ A_log,
                                                    const float* __restrict__ hinit,
                                                    const float* __restrict__ Dp,
                                                    f16* __restrict__ Ay) {
    __shared__ float Bs[CLEN * DSTATE];
    __shared__ float Cs[CLEN * DSTATE];
    const int d  = blockIdx.x * 256 + threadIdx.x;
    const int c  = blockIdx.y;
    const int l0 = c * CLEN;
    for (int i = threadIdx.x; i < CLEN * DSTATE; i += 256) {
        size_t roff = (size_t)(l0 + (i >> 4)) * DXW;
        Bs[i] = Dxz[roff + (i & 15)];
        Cs[i] = Dxz[roff + 16 + (i & 15)];
    }
    float Areg[DSTATE];
#pragma unroll
    for (int n = 0; n < DSTATE; n++) Areg[n] = -__expf(A_log[d * DSTATE + n]);
    float h[DSTATE];
#pragma unroll
    for (int n = 0; n < DSTATE; n++)
        h[n] = hinit[((size_t)c * DSTATE + n) * DINNER + d];
    const float Dv = Dp[d];
    const float w0 = Wc[d * 3 + 0], w1 = Wc[d * 3 + 1], w2 = Wc[d * 3 + 2];
    float xm = (l0 > 0) ? (float)Xb[(size_t)(l0 - 1) * DINNER + d] : 0.f;
    float x0 = (float)Xb[(size_t)l0 * DINNER + d];
    float ld_xp   = (float)Xb[(size_t)(l0 + 1) * DINNER + d];
    float ld_draw = Dxz[(size_t)l0 * DXW + 32 + d];
    float ld_z    = (float)Zb[(size_t)l0 * DINNER + d];
    __syncthreads();

    for (int t = 0; t < CLEN; t++) {
        const int l = l0 + t;
        float xp = ld_xp, draw = ld_draw, zv = ld_z;
        if (t + 1 < CLEN) {
            ld_xp   = (l + 2 < LSEQ) ? (float)Xb[(size_t)(l + 2) * DINNER + d] : 0.f;
            ld_draw = Dxz[(size_t)(l + 1) * DXW + 32 + d];
            ld_z    = (float)Zb[(size_t)(l + 1) * DINNER + d];
        }
        float v  = xm * w0 + x0 * w1 + xp * w2;
        float xcv = __fdividef(v, 1.f + __expf(-v));
        float dtv = (draw > 20.f) ? draw : __logf(1.f + __expf(draw));
        float u = dtv * xcv;
        float y = 0.f;
#pragma unroll
        for (int n = 0; n < DSTATE; n++) {
            float e = __expf(dtv * Areg[n]);
            h[n] = e * h[n] + u * Bs[t * DSTATE + n];
            y += h[n] * Cs[t * DSTATE + n];
        }
        float sz = __fdividef(zv, 1.f + __expf(-zv));
        Ay[(size_t)l * DINNER + d] = (f16)((y + xcv * Dv) * sz);
        xm = x0; x0 = xp;
    }
}

// ---------------------------------------------------------------------------
extern "C" void kernel_launch(void* const* d_in, const int* in_sizes, int n_in,
                              void* d_out, int out_size, void* d_ws, size_t ws_size,
                              hipStream_t stream) {
    const float* x     = (const float*)d_in[0];
    const float* W_in  = (const float*)d_in[1];
    const float* W_conv= (const float*)d_in[2];
    const float* W_out = (const float*)d_in[3];
    const float* A_log = (const float*)d_in[4];
    const float* Dp    = (const float*)d_in[5];
    float* out = (float*)d_out;

    // workspace carve-up (~130 MB; hinit aliases aprod — written in scan2
    // after each element is consumed, thread-private columns)
    float* ws  = (float*)d_ws;
    float* Dxz = ws;                                  // 4096*1568 f32
    float* ap  = Dxz + (size_t)LSEQ * DXW;            // 6,291,456 (aprod/hinit)
    float* he  = ap + (size_t)NCH * DSTATE * DINNER;  // 6,291,456
    f16* Ax = (f16*)(he + (size_t)NCH * DSTATE * DINNER); // 4096*768
    f16* Ay = Ax + (size_t)LSEQ * DIM;                // 4096*1536
    f16* Bw = Ay + (size_t)LSEQ * DINNER;             // 4736*768
    f16* Bo = Bw + (size_t)NPAD * DIM;                // 768*1536
    f16* Zb = Bo + (size_t)DIM * DINNER;              // 4096*1536
    f16* Xb = Zb + (size_t)LSEQ * DINNER;             // 4096*1536

    // 0) conversions (one kernel)
    cvt_all<<<E2 / 1024, 256, 0, stream>>>(x, W_in, W_out, Ax, Bw, Bo);

    // 1) xz = x @ W_in^T : 4-phase pipelined 256x128 tiles, counted vmcnt(6).
    //    16 M-tiles x 37 N-tiles = 592 blocks (= 8*74, XCD swizzle),
    //    col-major slab (B-locality per XCD).
    gemm1_pipe<<<592, 512, 0, stream>>>(Ax, Bw, Dxz, Xb, Zb);

    // 2) chunked scan: NCH=256 chunks of CLEN=16
    scan1_kernel<<<dim3(DINNER / 256, NCH), 256, 0, stream>>>(
        Dxz, Xb, W_conv, A_log, ap, he);
    scan2_kernel<<<(DINNER * DSTATE) / 256, 256, 0, stream>>>(ap, he);
    scan3_kernel<<<dim3(DINNER / 256, NCH), 256, 0, stream>>>(
        Dxz, Xb, Zb, W_conv, A_log, ap, Dp, Ay);

    // 3) out = yf @ W_out^T : BK=64, single-plane f16 W_out.
    //    64 M-tiles x 12 N-tiles = 768 blocks, row-major XCD slab (A-locality)
    gemm_f16<64, 64, 32, 32, 12, false, false><<<768, 256, 0, stream>>>(
        Ay, Bo, out, nullptr, nullptr, LSEQ, DIM, DINNER, DIM);
}

// Round 7
// 237.575 us; speedup vs baseline: 1.3705x; 1.0429x over previous
//
#include <hip/hip_runtime.h>
#include <hip/hip_bf16.h>
#include <math.h>

// Problem constants
#define LSEQ   4096
#define DIM    768
#define DINNER 1536
#define DSTATE 16
#define NCOLS  4640          // 3*DINNER + 2*DSTATE
#define NCH    256           // scan chunks (r6: halves serial chain)
#define CLEN   16            // steps per chunk
#define NPAD   4736          // W_in rows padded to 37*128
#define DXW    1568          // compact f32 width: B(16) C(16) delta(1536)

typedef _Float16 f16;
typedef __attribute__((ext_vector_type(4))) _Float16 f16x4;
typedef __attribute__((ext_vector_type(8))) _Float16 f16x8;
typedef __attribute__((ext_vector_type(4))) float f32x4;

// async global(16B/lane) -> LDS staging
__device__ __forceinline__ void gld_lds16(void* lds_dst, const void* gsrc) {
    __builtin_amdgcn_global_load_lds(
        (__attribute__((address_space(1))) void*)(gsrc),
        (__attribute__((address_space(3))) void*)(lds_dst), 16, 0, 0);
}

// ---------------------------------------------------------------------------
// GEMM1 (r2 winner): C = A[4096,768](f16) * B[4736,768]^T(f16).
//   BM=256 x BN=128, BK=64, 8 waves (512 thr), per-wave 64x64 (waves 4M x 2N).
//   3-deep cyclic LDS ring (144KB), prefetch distance 2, counted vmcnt(6),
//   4-phase quadrant schedule per K-tile (P00/P01/P10 with ds_read+stage,
//   P11 register-only), sched_barrier(0) after inline lgkmcnt(0) (rule #18).
//   LDS swizzle (verified conflict-free): global 16B block b of row r ->
//   LDS block b^(r&7); frag read fo=((q+4kk)^(m&7))<<3.
//   Epilogue: n0<1536 -> f16 Xb, <3072 -> f16 Zb, else f32 C (ldc=DXW).
//   Measured 47.2 (r2) / 56.7 (r6, same code) -> cross-run noise +-10us.
// ---------------------------------------------------------------------------
#define G1K    768
#define G1_NT  12            // K-tiles of 64
#define G1_BM  256
#define G1_BN  128
#define G1_RT  384           // rows per K-tile (BM+BN)
#define G1_LDSE (G1_RT * 64) // f16 elems per ring slot (48KB)

__global__ __launch_bounds__(512) void gemm1_pipe(const f16* __restrict__ A,
                                                  const f16* __restrict__ B,
                                                  float* __restrict__ C,
                                                  f16* __restrict__ Xb,
                                                  f16* __restrict__ Zb) {
    __shared__ __align__(16) f16 S[3 * G1_LDSE];   // 144 KB ring

    const int P   = gridDim.x >> 3;                // XCD swizzle: 592 = 8*74
    const int idx = (blockIdx.x & 7) * P + (blockIdx.x >> 3);
    const int m0  = (idx & 15) * G1_BM;            // 16 M-tiles: B-locality slab
    const int n0  = (idx >> 4) * G1_BN;            // 37 N-tiles

    const int tid  = threadIdx.x;
    const int w    = tid >> 6;                     // wave 0..7
    const int lane = tid & 63;
    const int wr   = w >> 1;                       // 0..3 (M)
    const int wc   = w & 1;                        // 0..1 (N)
    const int m    = lane & 15;                    // fragment row(A)/col(B)
    const int q    = lane >> 4;                    // quad
    const int rl8  = lane >> 3;                    // staging: row in 8-row group
    const int bsel = lane & 7;                     // staging: 16B-block index

    // staging map: 48 x 1KB instrs per K-tile; wave w takes t = w + 8*s.
    const f16* gb[6];
#pragma unroll
    for (int s = 0; s < 6; ++s) {
        const int rl  = (w + 8 * s) * 8 + rl8;
        const int blk = bsel ^ (rl & 7);
        gb[s] = (rl < G1_BM) ? A + (size_t)(m0 + rl) * G1K + blk * 8
                             : B + (size_t)(n0 + rl - G1_BM) * G1K + blk * 8;
    }

    f32x4 acc[4][4];
#pragma unroll
    for (int i = 0; i < 4; i++)
#pragma unroll
        for (int j = 0; j < 4; j++) acc[i][j] = (f32x4){0.f, 0.f, 0.f, 0.f};

    auto stg2 = [&](int kt, int s0) {  // issue 2 of K-tile kt's 6 staging instrs
        f16* dst = S + (kt % 3) * G1_LDSE;
#pragma unroll
        for (int s = s0; s < s0 + 2; ++s)
            gld_lds16(dst + (w + 8 * s) * 512, gb[s] + kt * 64);
    };
    auto stg6 = [&](int kt) {
        f16* dst = S + (kt % 3) * G1_LDSE;
#pragma unroll
        for (int s = 0; s < 6; ++s)
            gld_lds16(dst + (w + 8 * s) * 512, gb[s] + kt * 64);
    };

    // prologue: tiles 0 and 1 in flight (12 outstanding/wave)
    stg6(0);
    stg6(1);

#pragma unroll
    for (int kt = 0; kt < G1_NT; ++kt) {
        // drain tile kt's 6 loads (oldest); tile kt+1's 6 stay in flight.
        if (kt < G1_NT - 1) asm volatile("s_waitcnt vmcnt(6)" ::: "memory");
        else                asm volatile("s_waitcnt vmcnt(0)" ::: "memory");
        __builtin_amdgcn_s_barrier();   // all waves' stg(kt) landed; slot
                                        // (kt-1)%3's readers are all past.
        const f16* As = S + (kt % 3) * G1_LDSE;
        const f16* Bs = As + G1_BM * 64;
        const bool pf = (kt + 2 < G1_NT);

        f16x8 af0[2][2], af2[2][2], bh0[2][2], bh2[2][2]; // [kk][half-idx]

        // ---- P00: read af01 + bh01 (8), stage 2, MFMA quadrant (i01 x j01)
#pragma unroll
        for (int kk = 0; kk < 2; ++kk) {
            const int fo = (((q + 4 * kk) ^ (m & 7)) << 3);
#pragma unroll
            for (int i = 0; i < 2; ++i) {
                af0[kk][i] = *(const f16x8*)&As[(wr * 64 + i * 16 + m) * 64 + fo];
                bh0[kk][i] = *(const f16x8*)&Bs[(wc * 64 + i * 16 + m) * 64 + fo];
            }
        }
        if (pf) stg2(kt + 2, 0);
        __builtin_amdgcn_s_barrier();
        asm volatile("s_waitcnt lgkmcnt(0)" ::: "memory");
        __builtin_amdgcn_sched_barrier(0);
        __builtin_amdgcn_s_setprio(1);
#pragma unroll
        for (int kk = 0; kk < 2; ++kk)
#pragma unroll
            for (int i = 0; i < 2; ++i)
#pragma unroll
                for (int j = 0; j < 2; ++j)
                    acc[i][j] = __builtin_amdgcn_mfma_f32_16x16x32_f16(
                        af0[kk][i], bh0[kk][j], acc[i][j], 0, 0, 0);
        __builtin_amdgcn_s_setprio(0);

        // ---- P01: read bh23 (4), stage 2, MFMA quadrant (i01 x j23)
#pragma unroll
        for (int kk = 0; kk < 2; ++kk) {
            const int fo = (((q + 4 * kk) ^ (m & 7)) << 3);
#pragma unroll
            for (int j = 0; j < 2; ++j)
                bh2[kk][j] = *(const f16x8*)&Bs[(wc * 64 + (j + 2) * 16 + m) * 64 + fo];
        }
        if (pf) stg2(kt + 2, 2);
        __builtin_amdgcn_s_barrier();
        asm volatile("s_waitcnt lgkmcnt(0)" ::: "memory");
        __builtin_amdgcn_sched_barrier(0);
        __builtin_amdgcn_s_setprio(1);
#pragma unroll
        for (int kk = 0; kk < 2; ++kk)
#pragma unroll
            for (int i = 0; i < 2; ++i)
#pragma unroll
                for (int j = 0; j < 2; ++j)
                    acc[i][j + 2] = __builtin_amdgcn_mfma_f32_16x16x32_f16(
                        af0[kk][i], bh2[kk][j], acc[i][j + 2], 0, 0, 0);
        __builtin_amdgcn_s_setprio(0);

        // ---- P10: read af23 (4), stage 2, MFMA quadrant (i23 x j01)
#pragma unroll
        for (int kk = 0; kk < 2; ++kk) {
            const int fo = (((q + 4 * kk) ^ (m & 7)) << 3);
#pragma unroll
            for (int i = 0; i < 2; ++i)
                af2[kk][i] = *(const f16x8*)&As[(wr * 64 + (i + 2) * 16 + m) * 64 + fo];
        }
        if (pf) stg2(kt + 2, 4);
        __builtin_amdgcn_s_barrier();
        asm volatile("s_waitcnt lgkmcnt(0)" ::: "memory");
        __builtin_amdgcn_sched_barrier(0);
        __builtin_amdgcn_s_setprio(1);
#pragma unroll
        for (int kk = 0; kk < 2; ++kk)
#pragma unroll
            for (int i = 0; i < 2; ++i)
#pragma unroll
                for (int j = 0; j < 2; ++j)
                    acc[i + 2][j] = __builtin_amdgcn_mfma_f32_16x16x32_f16(
                        af2[kk][i], bh0[kk][j], acc[i + 2][j], 0, 0, 0);
        __builtin_amdgcn_s_setprio(0);

        // ---- P11: register-only MFMA quadrant (i23 x j23), no barrier needed
        __builtin_amdgcn_s_setprio(1);
#pragma unroll
        for (int kk = 0; kk < 2; ++kk)
#pragma unroll
            for (int i = 0; i < 2; ++i)
#pragma unroll
                for (int j = 0; j < 2; ++j)
                    acc[i + 2][j + 2] = __builtin_amdgcn_mfma_f32_16x16x32_f16(
                        af2[kk][i], bh2[kk][j], acc[i + 2][j + 2], 0, 0, 0);
        __builtin_amdgcn_s_setprio(0);
    }

    // epilogue: C/D layout col=lane&15, row=q*4+reg
    if (n0 < DINNER) {                     // x_inner cols -> f16 Xb
#pragma unroll
        for (int i = 0; i < 4; i++)
#pragma unroll
            for (int j = 0; j < 4; j++) {
                const int col  = n0 + wc * 64 + j * 16 + m;
                const int rowb = m0 + wr * 64 + i * 16 + q * 4;
#pragma unroll
                for (int r = 0; r < 4; r++)
                    Xb[(size_t)(rowb + r) * DINNER + col] = (f16)acc[i][j][r];
            }
        return;
    }
    if (n0 < 2 * DINNER) {                 // z cols -> f16 Zb
#pragma unroll
        for (int i = 0; i < 4; i++)
#pragma unroll
            for (int j = 0; j < 4; j++) {
                const int col  = n0 - DINNER + wc * 64 + j * 16 + m;
                const int rowb = m0 + wr * 64 + i * 16 + q * 4;
#pragma unroll
                for (int r = 0; r < 4; r++)
                    Zb[(size_t)(rowb + r) * DINNER + col] = (f16)acc[i][j][r];
            }
        return;
    }
#pragma unroll
    for (int i = 0; i < 4; i++)            // B|C|delta -> f32 C at ldc=DXW
#pragma unroll
        for (int j = 0; j < 4; j++) {
            const int col = n0 - 2 * DINNER + wc * 64 + j * 16 + m;
            if (col >= DXW) continue;
            const int rowb = m0 + wr * 64 + i * 16 + q * 4;
#pragma unroll
            for (int r = 0; r < 4; r++)
                C[(size_t)(rowb + r) * DXW + col] = acc[i][j][r];
        }
}

// ---------------------------------------------------------------------------
// GEMM2 (r7: pipelined): out = Ay[4096,1536](f16) * Bo[768,1536]^T(f16).
//   BM=BN=64, BK=64, 4 waves (256 thr), per-wave 32x32 (waves 2M x 2N).
//   K=1536 -> 24 K-tiles: deepest pipeline in the app. Ring of 3 x 16KB =
//   48KB -> exactly 3 blocks/CU at the 768-block grid (full co-residency).
//   Counted vmcnt(4): tile kt+1's 4 staging loads/wave stay in flight across
//   the (single) per-tile barrier — the r0->r1 gemm1 lever, deeper K here.
//   Same conflict-free XOR staging/read swizzle as gemm1.
// ---------------------------------------------------------------------------
#define G2K    1536
#define G2_NT  24            // K-tiles of 64
#define G2_LDSE (128 * 64)   // f16 elems per ring slot (16KB)

__global__ __launch_bounds__(256) void gemm2_pipe(const f16* __restrict__ A,
                                                  const f16* __restrict__ B,
                                                  float* __restrict__ C) {
    __shared__ __align__(16) f16 S[3 * G2_LDSE];   // 48 KB ring

    const int P   = gridDim.x >> 3;                // XCD swizzle: 768 = 8*96
    const int idx = (blockIdx.x & 7) * P + (blockIdx.x >> 3);
    const int m0  = (idx / 12) * 64;               // 64 M-tiles (A-locality slab)
    const int n0  = (idx % 12) * 64;               // 12 N-tiles

    const int tid  = threadIdx.x;
    const int w    = tid >> 6;                     // wave 0..3
    const int lane = tid & 63;
    const int wr   = w >> 1;                       // 0..1 (M)
    const int wc   = w & 1;                        // 0..1 (N)
    const int m    = lane & 15;
    const int q    = lane >> 4;
    const int rl8  = lane >> 3;
    const int bsel = lane & 7;

    // staging map: 16 x 1KB instrs per K-tile; wave w takes t = w + 4*s.
    const f16* gb[4];
#pragma unroll
    for (int s = 0; s < 4; ++s) {
        const int rl  = (w + 4 * s) * 8 + rl8;
        const int blk = bsel ^ (rl & 7);
        gb[s] = (rl < 64) ? A + (size_t)(m0 + rl) * G2K + blk * 8
                          : B + (size_t)(n0 + rl - 64) * G2K + blk * 8;
    }

    f32x4 acc[2][2];
#pragma unroll
    for (int i = 0; i < 2; i++)
#pragma unroll
        for (int j = 0; j < 2; j++) acc[i][j] = (f32x4){0.f, 0.f, 0.f, 0.f};

    auto stg = [&](int kt) {
        f16* dst = S + (kt % 3) * G2_LDSE;
#pragma unroll
        for (int s = 0; s < 4; ++s)
            gld_lds16(dst + (w + 4 * s) * 512, gb[s] + kt * 64);
    };

    stg(0);
    stg(1);

#pragma unroll
    for (int kt = 0; kt < G2_NT; ++kt) {
        // drain tile kt's 4 loads (oldest); tile kt+1's 4 stay in flight.
        if (kt < G2_NT - 1) asm volatile("s_waitcnt vmcnt(4)" ::: "memory");
        else                asm volatile("s_waitcnt vmcnt(0)" ::: "memory");
        __builtin_amdgcn_s_barrier();   // tile kt fully staged; slot (kt-1)%3's
                                        // readers (tile kt-1, pre-barrier) done.
        if (kt + 2 < G2_NT) stg(kt + 2);

        const f16* As = S + (kt % 3) * G2_LDSE;
        const f16* Bs = As + 64 * 64;

        f16x8 af[2][2], bh[2][2];      // [kk][tile]
#pragma unroll
        for (int kk = 0; kk < 2; ++kk) {
            const int fo = (((q + 4 * kk) ^ (m & 7)) << 3);
#pragma unroll
            for (int i = 0; i < 2; ++i) {
                af[kk][i] = *(const f16x8*)&As[(wr * 32 + i * 16 + m) * 64 + fo];
                bh[kk][i] = *(const f16x8*)&Bs[(wc * 32 + i * 16 + m) * 64 + fo];
            }
        }
        asm volatile("s_waitcnt lgkmcnt(0)" ::: "memory");
        __builtin_amdgcn_sched_barrier(0);
        __builtin_amdgcn_s_setprio(1);
#pragma unroll
        for (int kk = 0; kk < 2; ++kk)
#pragma unroll
            for (int i = 0; i < 2; ++i)
#pragma unroll
                for (int j = 0; j < 2; ++j)
                    acc[i][j] = __builtin_amdgcn_mfma_f32_16x16x32_f16(
                        af[kk][i], bh[kk][j], acc[i][j], 0, 0, 0);
        __builtin_amdgcn_s_setprio(0);
    }

    // epilogue: C/D layout col=lane&15, row=q*4+reg
#pragma unroll
    for (int i = 0; i < 2; i++)
#pragma unroll
        for (int j = 0; j < 2; j++) {
            const int col  = n0 + wc * 32 + j * 16 + m;
            const int rowb = m0 + wr * 32 + i * 16 + q * 4;
#pragma unroll
            for (int r = 0; r < 4; r++)
                C[(size_t)(rowb + r) * DIM + col] = acc[i][j][r];
        }
}

// ---------------------------------------------------------------------------
// merged conversions: Ax (f16 x), Bw (f16 W_in, zero-padded), Bo (f16 W_out).
// r7: packed f16x4 (8B) stores instead of 4 scalar f16 stores.
// ---------------------------------------------------------------------------
#define E0 (LSEQ * DIM)            // 3,145,728
#define E1 (E0 + NPAD * DIM)       // + 3,637,248
#define E2 (E1 + DIM * DINNER)     // + 1,179,648

__global__ __launch_bounds__(256) void cvt_all(const float* __restrict__ x,
                                               const float* __restrict__ Wi,
                                               const float* __restrict__ Wo,
                                               f16* __restrict__ Ax,
                                               f16* __restrict__ Bw,
                                               f16* __restrict__ Bo) {
    int i = (blockIdx.x * 256 + threadIdx.x) * 4;
    if (i < E0) {
        float4 v = *(const float4*)(x + i);
        f16x4 o = {(f16)v.x, (f16)v.y, (f16)v.z, (f16)v.w};
        *(f16x4*)(Ax + i) = o;
    } else if (i < E1) {
        int e = i - E0;
        int n = e / DIM;
        if (n < NCOLS) {
            float4 v = *(const float4*)(Wi + e);
            f16x4 o = {(f16)v.x, (f16)v.y, (f16)v.z, (f16)v.w};
            *(f16x4*)(Bw + e) = o;
        } else {
            f16x4 o = {(f16)0.f, (f16)0.f, (f16)0.f, (f16)0.f};
            *(f16x4*)(Bw + e) = o;
        }
    } else if (i < E2) {
        int e = i - E1;
        float4 v = *(const float4*)(Wo + e);
        f16x4 o = {(f16)v.x, (f16)v.y, (f16)v.z, (f16)v.w};
        *(f16x4*)(Bo + e) = o;
    }
}

// ---------------------------------------------------------------------------
// scan phase 1 (r0 rolling form, CLEN=16): conv+silu+softplus fused; local
// scan h=0 -> h_end; aprod. Rolling scalar prefetch distance 1 (known-good;
// r4 full-CLEN arrays spilled, r5 group-pipeline was latency-worse).
// NCH=256: grid 6x256=1536 blocks -> 6 blocks/CU -> ~24 waves/CU.
// ---------------------------------------------------------------------------
__global__ __launch_bounds__(256) void scan1_kernel(const float* __restrict__ Dxz,
                                                    const f16* __restrict__ Xb,
                                                    const float* __restrict__ Wc,
                                                    const float* __restrict__ A_log,
                                                    float* __restrict__ aprod,
                                                    float* __restrict__ hend) {
    __shared__ float Bs[CLEN * DSTATE];
    const int d  = blockIdx.x * 256 + threadIdx.x;
    const int c  = blockIdx.y;
    const int l0 = c * CLEN;
    for (int i = threadIdx.x; i < CLEN * DSTATE; i += 256)
        Bs[i] = Dxz[(size_t)(l0 + (i >> 4)) * DXW + (i & 15)];
    float Areg[DSTATE];
#pragma unroll
    for (int n = 0; n < DSTATE; n++) Areg[n] = -__expf(A_log[d * DSTATE + n]);
    const float w0 = Wc[d * 3 + 0], w1 = Wc[d * 3 + 1], w2 = Wc[d * 3 + 2];
    float xm = (l0 > 0) ? (float)Xb[(size_t)(l0 - 1) * DINNER + d] : 0.f;
    float x0 = (float)Xb[(size_t)l0 * DINNER + d];
    float ld_xp   = (float)Xb[(size_t)(l0 + 1) * DINNER + d];
    float ld_draw = Dxz[(size_t)l0 * DXW + 32 + d];
    __syncthreads();

    float h[DSTATE];
#pragma unroll
    for (int n = 0; n < DSTATE; n++) h[n] = 0.f;
    float S = 0.f;

    for (int t = 0; t < CLEN; t++) {
        const int l = l0 + t;
        float xp = ld_xp, draw = ld_draw;
        if (t + 1 < CLEN) {
            ld_xp   = (l + 2 < LSEQ) ? (float)Xb[(size_t)(l + 2) * DINNER + d] : 0.f;
            ld_draw = Dxz[(size_t)(l + 1) * DXW + 32 + d];
        }
        float v  = xm * w0 + x0 * w1 + xp * w2;
        float xcv = __fdividef(v, 1.f + __expf(-v));
        float dtv = (draw > 20.f) ? draw : __logf(1.f + __expf(draw));
        float u = dtv * xcv;
        S += dtv;
#pragma unroll
        for (int n = 0; n < DSTATE; n++) {
            float e = __expf(dtv * Areg[n]);
            h[n] = e * h[n] + u * Bs[t * DSTATE + n];
        }
        xm = x0; x0 = xp;
    }
#pragma unroll
    for (int n = 0; n < DSTATE; n++) {
        size_t idx = ((size_t)c * DSTATE + n) * DINNER + d;
        aprod[idx] = __expf(S * Areg[n]);
        hend[idx]  = h[n];
    }
}

// ---------------------------------------------------------------------------
// scan phase 2: sequential over NCH chunk summaries. 4-deep batched prefetch
// (two named 4-buffers, static indices — rule #20). Writes hinit IN-PLACE
// into the aprod buffer (thread-private column, read-before-write by 4-8
// chunks -> race-free).
// ---------------------------------------------------------------------------
__global__ __launch_bounds__(256) void scan2_kernel(float* __restrict__ aphi,
                                                    const float* __restrict__ hend) {
    const int g = blockIdx.x * 256 + threadIdx.x;
    const size_t S = (size_t)DSTATE * DINNER;
    float aA[4], eA[4], aB[4], eB[4];
#pragma unroll
    for (int k = 0; k < 4; ++k) {
        aA[k] = aphi[g + (size_t)k * S];
        eA[k] = hend[g + (size_t)k * S];
    }
    float h = 0.f;
    for (int c = 0; c < NCH; c += 8) {
#pragma unroll
        for (int k = 0; k < 4; ++k) {      // prefetch B: chunks c+4..c+7
            aB[k] = aphi[g + (size_t)(c + 4 + k) * S];
            eB[k] = hend[g + (size_t)(c + 4 + k) * S];
        }
#pragma unroll
        for (int k = 0; k < 4; ++k) {      // process A: chunks c..c+3
            aphi[g + (size_t)(c + k) * S] = h;     // hinit (in-place)
            h = aA[k] * h + eA[k];
        }
        if (c + 8 < NCH) {
#pragma unroll
            for (int k = 0; k < 4; ++k) {  // prefetch A: chunks c+8..c+11
                aA[k] = aphi[g + (size_t)(c + 8 + k) * S];
                eA[k] = hend[g + (size_t)(c + 8 + k) * S];
            }
        }
#pragma unroll
        for (int k = 0; k < 4; ++k) {      // process B: chunks c+4..c+7
            aphi[g + (size_t)(c + 4 + k) * S] = h; // hinit (in-place)
            h = aB[k] * h + eB[k];
        }
    }
}

// ---------------------------------------------------------------------------
// scan phase 3 (r0 rolling form, CLEN=16): replay from h_init (aliased into
// the aprod buffer); z-gate from f16 Zb; emit f16 Ay.
// ---------------------------------------------------------------------------
__global__ __launch_bounds__(256) void scan3_kernel(const float* __restrict__ Dxz,
                                                    const f16* __restrict__ Xb,
                                                    const f16* __restrict__ Zb,
                                                    const float* __restrict__ Wc,
                                                    const float* __restrict__ A_log,
                                                    const float* __restrict__ hinit,
                                                    const float* __restrict__ Dp,
                                                    f16* __restrict__ Ay) {
    __shared__ float Bs[CLEN * DSTATE];
    __shared__ float Cs[CLEN * DSTATE];
    const int d  = blockIdx.x * 256 + threadIdx.x;
    const int c  = blockIdx.y;
    const int l0 = c * CLEN;
    for (int i = threadIdx.x; i < CLEN * DSTATE; i += 256) {
        size_t roff = (size_t)(l0 + (i >> 4)) * DXW;
        Bs[i] = Dxz[roff + (i & 15)];
        Cs[i] = Dxz[roff + 16 + (i & 15)];
    }
    float Areg[DSTATE];
#pragma unroll
    for (int n = 0; n < DSTATE; n++) Areg[n] = -__expf(A_log[d * DSTATE + n]);
    float h[DSTATE];
#pragma unroll
    for (int n = 0; n < DSTATE; n++)
        h[n] = hinit[((size_t)c * DSTATE + n) * DINNER + d];
    const float Dv = Dp[d];
    const float w0 = Wc[d * 3 + 0], w1 = Wc[d * 3 + 1], w2 = Wc[d * 3 + 2];
    float xm = (l0 > 0) ? (float)Xb[(size_t)(l0 - 1) * DINNER + d] : 0.f;
    float x0 = (float)Xb[(size_t)l0 * DINNER + d];
    float ld_xp   = (float)Xb[(size_t)(l0 + 1) * DINNER + d];
    float ld_draw = Dxz[(size_t)l0 * DXW + 32 + d];
    float ld_z    = (float)Zb[(size_t)l0 * DINNER + d];
    __syncthreads();

    for (int t = 0; t < CLEN; t++) {
        const int l = l0 + t;
        float xp = ld_xp, draw = ld_draw, zv = ld_z;
        if (t + 1 < CLEN) {
            ld_xp   = (l + 2 < LSEQ) ? (float)Xb[(size_t)(l + 2) * DINNER + d] : 0.f;
            ld_draw = Dxz[(size_t)(l + 1) * DXW + 32 + d];
            ld_z    = (float)Zb[(size_t)(l + 1) * DINNER + d];
        }
        float v  = xm * w0 + x0 * w1 + xp * w2;
        float xcv = __fdividef(v, 1.f + __expf(-v));
        float dtv = (draw > 20.f) ? draw : __logf(1.f + __expf(draw));
        float u = dtv * xcv;
        float y = 0.f;
#pragma unroll
        for (int n = 0; n < DSTATE; n++) {
            float e = __expf(dtv * Areg[n]);
            h[n] = e * h[n] + u * Bs[t * DSTATE + n];
            y += h[n] * Cs[t * DSTATE + n];
        }
        float sz = __fdividef(zv, 1.f + __expf(-zv));
        Ay[(size_t)l * DINNER + d] = (f16)((y + xcv * Dv) * sz);
        xm = x0; x0 = xp;
    }
}

// ---------------------------------------------------------------------------
extern "C" void kernel_launch(void* const* d_in, const int* in_sizes, int n_in,
                              void* d_out, int out_size, void* d_ws, size_t ws_size,
                              hipStream_t stream) {
    const float* x     = (const float*)d_in[0];
    const float* W_in  = (const float*)d_in[1];
    const float* W_conv= (const float*)d_in[2];
    const float* W_out = (const float*)d_in[3];
    const float* A_log = (const float*)d_in[4];
    const float* Dp    = (const float*)d_in[5];
    float* out = (float*)d_out;

    // workspace carve-up (~130 MB; hinit aliases aprod — written in scan2
    // after each element is consumed, thread-private columns)
    float* ws  = (float*)d_ws;
    float* Dxz = ws;                                  // 4096*1568 f32
    float* ap  = Dxz + (size_t)LSEQ * DXW;            // 6,291,456 (aprod/hinit)
    float* he  = ap + (size_t)NCH * DSTATE * DINNER;  // 6,291,456
    f16* Ax = (f16*)(he + (size_t)NCH * DSTATE * DINNER); // 4096*768
    f16* Ay = Ax + (size_t)LSEQ * DIM;                // 4096*1536
    f16* Bw = Ay + (size_t)LSEQ * DINNER;             // 4736*768
    f16* Bo = Bw + (size_t)NPAD * DIM;                // 768*1536
    f16* Zb = Bo + (size_t)DIM * DINNER;              // 4096*1536
    f16* Xb = Zb + (size_t)LSEQ * DINNER;             // 4096*1536

    // 0) conversions (one kernel, f16x4 packed stores)
    cvt_all<<<E2 / 1024, 256, 0, stream>>>(x, W_in, W_out, Ax, Bw, Bo);

    // 1) xz = x @ W_in^T : 4-phase pipelined 256x128 tiles, counted vmcnt(6).
    //    16 M-tiles x 37 N-tiles = 592 blocks (= 8*74, XCD swizzle),
    //    col-major slab (B-locality per XCD).
    gemm1_pipe<<<592, 512, 0, stream>>>(Ax, Bw, Dxz, Xb, Zb);

    // 2) chunked scan: NCH=256 chunks of CLEN=16
    scan1_kernel<<<dim3(DINNER / 256, NCH), 256, 0, stream>>>(
        Dxz, Xb, W_conv, A_log, ap, he);
    scan2_kernel<<<(DINNER * DSTATE) / 256, 256, 0, stream>>>(ap, he);
    scan3_kernel<<<dim3(DINNER / 256, NCH), 256, 0, stream>>>(
        Dxz, Xb, Zb, W_conv, A_log, ap, Dp, Ay);

    // 3) out = Ay @ W_out^T : pipelined ring-of-3, counted vmcnt(4), 24 K-tiles.
    //    64 M-tiles x 12 N-tiles = 768 blocks (= 8*96, XCD swizzle, A-locality)
    gemm2_pipe<<<768, 256, 0, stream>>>(Ay, Bo, out);
}